// Round 8
// baseline (676.569 us; speedup 1.0000x reference)
//
#include <hip/hip_runtime.h>
#include <math.h>

#define B_Q   128
#define DIM   512
#define NCORP 500000
#define NCH   16               // K chunks of 32 (512/32)
#define G_SCAN 256             // scan grid: 1 block/CU (LDS-capped)
#define WAVES  8
#define WSTRIDE (G_SCAN * WAVES)   // 2048 waves
#define UNITS  (NCORP / 16)        // 31250 16-row units (exact)

typedef short short8 __attribute__((ext_vector_type(8)));
typedef float floatx4 __attribute__((ext_vector_type(4)));

__device__ __forceinline__ unsigned short bf16_rne(float x) {
    unsigned u = __float_as_uint(x);
    return (unsigned short)((u + 0x7FFFu + ((u >> 16) & 1u)) >> 16);
}

// pack two f32 -> two bf16 (truncation) in one v_perm
__device__ __forceinline__ unsigned pack2(float hi, float lo) {
    return __builtin_amdgcn_perm(__float_as_uint(hi), __float_as_uint(lo),
                                 0x07060302u);
}

__device__ __forceinline__ void ins3(float s, int id,
                                     float& b0, float& b1, float& b2,
                                     int& i0, int& i1, int& i2) {
    if (s > b0)      { b2 = b1; i2 = i1; b1 = b0; i1 = i0; b0 = s; i0 = id; }
    else if (s > b1) { b2 = b1; i2 = i1; b1 = s;  i1 = id; }
    else if (s > b2) { b2 = s;  i2 = id; }
}

__device__ __forceinline__ void ins2(float s, int id,
                                     float& b0, float& b1, int& i0, int& i1) {
    if (s > b0)      { b1 = b0; i1 = i0; b0 = s; i0 = id; }
    else if (s > b1) { b1 = s;  i1 = id; }
}

__device__ __forceinline__ void ins8(float s, int id, float* bs, int* bi) {
#pragma unroll
    for (int j = 0; j < 8; ++j) {
        if (s > bs[j]) {
            float tf = bs[j]; int tx = bi[j];
            bs[j] = s; bi[j] = id; s = tf; id = tx;
        }
    }
}

// async global -> LDS, 16B/lane, linear dest (wave-uniform base + lane*16)
__device__ __forceinline__ void gload16(const float* g, float* l) {
    __builtin_amdgcn_global_load_lds(
        (const __attribute__((address_space(1))) unsigned*)g,
        (__attribute__((address_space(3))) unsigned*)l, 16, 0, 0);
}

// ---------------------------------------------------------------------------
// Kernel A: query = query_r @ W ; L2-normalize ; write
//  (a) exact qn f32 row-major (for rescore)
//  (b) bf16 MFMA B-fragment-linear: idx = kc*4096 + qg*512 + (g*16+q15)*8 + e
// ---------------------------------------------------------------------------
__global__ void proj_kernel(const float* __restrict__ qr,
                            const float* __restrict__ W,
                            float* __restrict__ qn,
                            unsigned short* __restrict__ qfrag) {
    __shared__ float qrow[DIM];
    __shared__ float red[256];
    const int b = blockIdx.x;
    const int t = threadIdx.x;

    qrow[t]       = qr[b * DIM + t];
    qrow[t + 256] = qr[b * DIM + t + 256];
    __syncthreads();

    float acc0 = 0.f, acc1 = 0.f;
#pragma unroll 8
    for (int k = 0; k < DIM; ++k) {
        const float q = qrow[k];
        acc0 = fmaf(q, W[k * DIM + t],       acc0);
        acc1 = fmaf(q, W[k * DIM + t + 256], acc1);
    }

    red[t] = acc0 * acc0 + acc1 * acc1;
    __syncthreads();
    for (int s = 128; s > 0; s >>= 1) {
        if (t < s) red[t] += red[t + s];
        __syncthreads();
    }
    const float inv = 1.0f / fmaxf(sqrtf(red[0]), 1e-6f);

    const int qg = b >> 4, q15 = b & 15;
#pragma unroll
    for (int half = 0; half < 2; ++half) {
        const int d = t + half * 256;
        const float x = (half == 0 ? acc0 : acc1) * inv;
        qn[b * DIM + d] = x;
        const int kc = d >> 5, kk = d & 31, g = kk >> 3, e = kk & 7;
        qfrag[(size_t)kc * 4096 + qg * 512 + (g * 16 + q15) * 8 + e] = bf16_rne(x);
    }
}

// ---------------------------------------------------------------------------
// Kernel B: barrier-free MFMA cosine scan.
//  LDS (160 KB): Q resident 128 KB + per-wave private 2-deep corpus chunk
//  ring (8 waves x 2 x 2 KB). Corpus staged via global_load_lds with
//  XOR-swizzled source; reads de-swizzle. Sync = per-wave vmcnt(2) only.
// ---------------------------------------------------------------------------
__global__ __launch_bounds__(512, 2) void scan_kernel(
        const float* __restrict__ corpus,
        const unsigned short* __restrict__ qfrag,
        float* __restrict__ cand_s,
        int*   __restrict__ cand_i) {
    __shared__ __align__(16) unsigned char smem[163840];
    unsigned short* Qlds = (unsigned short*)smem;        // 128 KB
    float*          ring = (float*)(smem + 131072);      // 32 KB

    const int t = threadIdx.x;
    const int w = t >> 6, l = t & 63;
    const int h = l >> 4, q15 = l & 15;

    // ---- stage Q into LDS once (linear 128 KB copy) ----
    {
        const uint4* src = (const uint4*)qfrag;
        uint4* dst = (uint4*)Qlds;
#pragma unroll
        for (int i = 0; i < 16; ++i)
            dst[t + 512 * i] = src[t + 512 * i];
    }
    __syncthreads();

    float* ringw = ring + w * 1024;          // 2 bufs x 512 f32, wave-private

    // staging lane constants: instr i covers rows i*8+srow, slot l&7
    const int srow = l >> 3;                              // 0..7
    const int scol = ((l & 7) ^ srow) * 4;                // inverse-swizzled col
    // read lane constants (de-swizzle)
    const int rbase = q15 * 32;
    const int c0 = ((h * 2)     ^ (q15 & 7)) * 4;
    const int c1 = ((h * 2 + 1) ^ (q15 & 7)) * 4;

    float ts[8][2]; int ti[8][2];
#pragma unroll
    for (int qg = 0; qg < 8; ++qg) {
        ts[qg][0] = -1e30f; ts[qg][1] = -1e30f;
        ti[qg][0] = -1;     ti[qg][1] = -1;
    }

    const int gw = blockIdx.x * WAVES + w;

    // stage cursor: runs 1 chunk ahead; clamp at tail so 2 loads always issue
    int stile = gw, skc = 0;

#define STAGE(BUF) do {                                                        \
        const int stc = (stile < UNITS) ? stile : (UNITS - 1);                 \
        const size_t rowb = (size_t)stc * 16;                                  \
        gload16(corpus + (rowb + srow) * DIM + skc * 32 + scol,                \
                ringw + (BUF) * 512);                                          \
        gload16(corpus + (rowb + 8 + srow) * DIM + skc * 32 + scol,            \
                ringw + (BUF) * 512 + 256);                                    \
        if (++skc == NCH) { skc = 0; stile += WSTRIDE; }                       \
    } while (0)

    STAGE(0);                                  // chunk 0 in flight (2 loads)

    int cbuf = 1;                              // next stage destination
    for (int u = gw; u < UNITS; u += WSTRIDE) {
        floatx4 acc[8];
#pragma unroll
        for (int qg = 0; qg < 8; ++qg)
#pragma unroll
            for (int j = 0; j < 4; ++j) acc[qg][j] = 0.f;
        float nsq = 0.f;

#pragma unroll
        for (int kc = 0; kc < NCH; ++kc) {
            STAGE(cbuf);                       // stage chunk+1 (outstanding: 4)
            __builtin_amdgcn_sched_barrier(0);
            asm volatile("s_waitcnt vmcnt(2)" ::: "memory");  // current chunk ready

            const float* Ab = ringw + (cbuf ^ 1) * 512 + rbase;
            const float4 f0 = *(const float4*)(Ab + c0);
            const float4 f1 = *(const float4*)(Ab + c1);

            const short8* qp = (const short8*)(Qlds + kc * 4096);
            short8 bq[8];
#pragma unroll
            for (int qg = 0; qg < 8; ++qg) bq[qg] = qp[qg * 64 + l];

            nsq += f0.x*f0.x + f0.y*f0.y + f0.z*f0.z + f0.w*f0.w
                 + f1.x*f1.x + f1.y*f1.y + f1.z*f1.z + f1.w*f1.w;

            uint4 ap;
            ap.x = pack2(f0.y, f0.x); ap.y = pack2(f0.w, f0.z);
            ap.z = pack2(f1.y, f1.x); ap.w = pack2(f1.w, f1.z);
            const short8 a = __builtin_bit_cast(short8, ap);

            acc[0] = __builtin_amdgcn_mfma_f32_16x16x32_bf16(a, bq[0], acc[0], 0, 0, 0);
            acc[1] = __builtin_amdgcn_mfma_f32_16x16x32_bf16(a, bq[1], acc[1], 0, 0, 0);
            acc[2] = __builtin_amdgcn_mfma_f32_16x16x32_bf16(a, bq[2], acc[2], 0, 0, 0);
            acc[3] = __builtin_amdgcn_mfma_f32_16x16x32_bf16(a, bq[3], acc[3], 0, 0, 0);
            acc[4] = __builtin_amdgcn_mfma_f32_16x16x32_bf16(a, bq[4], acc[4], 0, 0, 0);
            acc[5] = __builtin_amdgcn_mfma_f32_16x16x32_bf16(a, bq[5], acc[5], 0, 0, 0);
            acc[6] = __builtin_amdgcn_mfma_f32_16x16x32_bf16(a, bq[6], acc[6], 0, 0, 0);
            acc[7] = __builtin_amdgcn_mfma_f32_16x16x32_bf16(a, bq[7], acc[7], 0, 0, 0);

            cbuf ^= 1;
        }

        // full row norm: lanes l, l^16, l^32 cover the 4 k-slices
        float n = nsq;
        n += __shfl_xor(n, 16); n += __shfl_xor(n, 32);
        const float invn = 1.0f / fmaxf(sqrtf(n), 1e-6f);

        // scores -> per-lane running top2 per query group
#pragma unroll
        for (int reg = 0; reg < 4; ++reg) {
            const int m = h * 4 + reg;         // C row within unit
            const float iv = __shfl(invn, m, 64);
            const int r = u * 16 + m;
            if (r < NCORP) {
#pragma unroll
                for (int qg = 0; qg < 8; ++qg)
                    ins2(acc[qg][reg] * iv, r,
                         ts[qg][0], ts[qg][1], ti[qg][0], ti[qg][1]);
            }
        }
    }
#undef STAGE

    // ---- block merge: 32 slots x top2 per query -> per-block top-3 ----
    __syncthreads();                           // all waves done with Q/ring
    float* msc = (float*)smem;                 // [128][32][2] f32 = 32 KB
    int*   mid = (int*)(smem + 32768);         // 32 KB
#pragma unroll
    for (int qg = 0; qg < 8; ++qg) {
        const int q = qg * 16 + q15;
        const int slot = w * 4 + h;            // 0..31
#pragma unroll
        for (int j = 0; j < 2; ++j) {
            msc[(q * 32 + slot) * 2 + j] = ts[qg][j];
            mid[(q * 32 + slot) * 2 + j] = ti[qg][j];
        }
    }
    __syncthreads();
    if (t < B_Q) {
        float b0 = -1e30f, b1 = -1e30f, b2 = -1e30f;
        int   i0 = -1, i1 = -1, i2 = -1;
        for (int e = 0; e < 64; ++e)
            ins3(msc[t * 64 + e], mid[t * 64 + e], b0, b1, b2, i0, i1, i2);
        const size_t base = ((size_t)blockIdx.x * B_Q + t) * 3;
        cand_s[base + 0] = b0; cand_s[base + 1] = b1; cand_s[base + 2] = b2;
        cand_i[base + 0] = i0; cand_i[base + 1] = i1; cand_i[base + 2] = i2;
    }
}

// ---------------------------------------------------------------------------
// Kernel C: merge per-block candidates -> global approx top-8 per query.
// ---------------------------------------------------------------------------
__global__ void merge_topk_kernel(const float* __restrict__ cand_s,
                                  const int*   __restrict__ cand_i,
                                  int nblk,
                                  float* __restrict__ topT_s,
                                  int*   __restrict__ topT_i) {
    __shared__ float ls[256 * 8];
    __shared__ int   li[256 * 8];
    const int q = blockIdx.x;
    const int t = threadIdx.x;

    float bs[8]; int bi[8];
#pragma unroll
    for (int j = 0; j < 8; ++j) { bs[j] = -1e30f; bi[j] = -1; }

    for (int blk = t; blk < nblk; blk += 256) {
        const size_t base = ((size_t)blk * B_Q + q) * 3;
#pragma unroll
        for (int j = 0; j < 3; ++j)
            ins8(cand_s[base + j], cand_i[base + j], bs, bi);
    }
#pragma unroll
    for (int j = 0; j < 8; ++j) { ls[t * 8 + j] = bs[j]; li[t * 8 + j] = bi[j]; }
    __syncthreads();

    for (int s = 128; s > 0; s >>= 1) {
        if (t < s) {
#pragma unroll
            for (int j = 0; j < 8; ++j)
                ins8(ls[(t + s) * 8 + j], li[(t + s) * 8 + j], bs, bi);
#pragma unroll
            for (int j = 0; j < 8; ++j) { ls[t * 8 + j] = bs[j]; li[t * 8 + j] = bi[j]; }
        }
        __syncthreads();
    }
    if (t == 0) {
#pragma unroll
        for (int j = 0; j < 8; ++j) { topT_s[q * 8 + j] = bs[j]; topT_i[q * 8 + j] = bi[j]; }
    }
}

// ---------------------------------------------------------------------------
// Kernel D: exact f32 rescore of 8 candidates per query -> top-3 -> out.
// d_out: [0..383] scores f32, [384..767] indices stored as f32 values.
// ---------------------------------------------------------------------------
__global__ void rescore_kernel(const float* __restrict__ corpus,
                               const float* __restrict__ qn,
                               const int*   __restrict__ topT_i,
                               float* __restrict__ out) {
    __shared__ float qrow[DIM];
    __shared__ float sc[8];
    const int q = blockIdx.x;
    const int t = threadIdx.x;
    const int g = t >> 5;       // candidate 0..7
    const int lane = t & 31;

    qrow[t]       = qn[q * DIM + t];
    qrow[t + 256] = qn[q * DIM + t + 256];
    __syncthreads();

    const int r = topT_i[q * 8 + g];
    float d = 0.f, n = 0.f;
    if (r >= 0) {
        const float* row = corpus + (size_t)r * DIM;
        for (int j = lane; j < DIM; j += 32) {
            const float c = row[j];
            d = fmaf(qrow[j], c, d);
            n = fmaf(c, c, n);
        }
    }
#pragma unroll
    for (int m = 16; m > 0; m >>= 1) {
        d += __shfl_xor(d, m);
        n += __shfl_xor(n, m);
    }
    if (lane == 0)
        sc[g] = (r >= 0) ? d / fmaxf(sqrtf(n), 1e-6f) : -1e30f;
    __syncthreads();

    if (t == 0) {
        float b0 = -1e30f, b1 = -1e30f, b2 = -1e30f;
        int   i0 = 0, i1 = 0, i2 = 0;
#pragma unroll
        for (int e = 0; e < 8; ++e)
            ins3(sc[e], topT_i[q * 8 + e], b0, b1, b2, i0, i1, i2);
        out[q * 3 + 0] = b0;
        out[q * 3 + 1] = b1;
        out[q * 3 + 2] = b2;
        out[B_Q * 3 + q * 3 + 0] = (float)i0;
        out[B_Q * 3 + q * 3 + 1] = (float)i1;
        out[B_Q * 3 + q * 3 + 2] = (float)i2;
    }
}

// ---------------------------------------------------------------------------
extern "C" void kernel_launch(void* const* d_in, const int* in_sizes, int n_in,
                              void* d_out, int out_size, void* d_ws, size_t ws_size,
                              hipStream_t stream) {
    const float* qr     = (const float*)d_in[0];  // [128,512]
    const float* corpus = (const float*)d_in[1];  // [500000,512]
    const float* W      = (const float*)d_in[2];  // [512,512]

    float* out = (float*)d_out;
    char*  ws  = (char*)d_ws;

    float*          qn     = (float*)ws;                      // 256 KB
    unsigned short* qfrag  = (unsigned short*)(ws + 262144);  // 128 KB
    float*          topT_s = (float*)(ws + 393216);           // 4 KB
    int*            topT_i = (int*)(ws + 397312);             // 4 KB
    const size_t head = 401408;

    float* cand_s = (float*)(ws + head);                      // 256*128*3 f32
    int*   cand_i = (int*)(ws + head + (size_t)G_SCAN * B_Q * 3 * sizeof(float));

    proj_kernel<<<B_Q, 256, 0, stream>>>(qr, W, qn, qfrag);
    scan_kernel<<<G_SCAN, 512, 0, stream>>>(corpus, qfrag, cand_s, cand_i);
    merge_topk_kernel<<<B_Q, 256, 0, stream>>>(cand_s, cand_i, G_SCAN, topT_s, topT_i);
    rescore_kernel<<<B_Q, 256, 0, stream>>>(corpus, qn, topT_i, out);
}

// Round 9
// 619.886 us; speedup vs baseline: 1.0914x; 1.0914x over previous
//
#include <hip/hip_runtime.h>
#include <math.h>

#define B_Q   128
#define DIM   512
#define NCORP 500000
#define NCH   16               // K chunks of 32 (512/32)
#define NTILES (NCORP / 16)    // 31250 16-row tiles (exact)
#define G_SCAN 256             // 1 block/CU (160 KB LDS)

typedef short short8 __attribute__((ext_vector_type(8)));
typedef float floatx4 __attribute__((ext_vector_type(4)));

__device__ __forceinline__ unsigned short bf16_rne(float x) {
    unsigned u = __float_as_uint(x);
    return (unsigned short)((u + 0x7FFFu + ((u >> 16) & 1u)) >> 16);
}

// pack two f32 -> two bf16 (truncation) in one v_perm: result = [hi:lo]
__device__ __forceinline__ unsigned pack2(float hi, float lo) {
    return __builtin_amdgcn_perm(__float_as_uint(hi), __float_as_uint(lo),
                                 0x07060302u);
}

__device__ __forceinline__ void ins3(float s, int id,
                                     float& b0, float& b1, float& b2,
                                     int& i0, int& i1, int& i2) {
    if (s > b0)      { b2 = b1; i2 = i1; b1 = b0; i1 = i0; b0 = s; i0 = id; }
    else if (s > b1) { b2 = b1; i2 = i1; b1 = s;  i1 = id; }
    else if (s > b2) { b2 = s;  i2 = id; }
}

__device__ __forceinline__ void ins8(float s, int id, float* bs, int* bi) {
#pragma unroll
    for (int j = 0; j < 8; ++j) {
        if (s > bs[j]) {
            float tf = bs[j]; int tx = bi[j];
            bs[j] = s; bi[j] = id; s = tf; id = tx;
        }
    }
}

// ---------------------------------------------------------------------------
// Kernel A: query = query_r @ W ; L2-normalize ; write
//  (a) exact qn f32 row-major (for rescore)
//  (b) bf16 MFMA B-fragment-linear: idx = kc*4096 + qg*512 + (g*16+q15)*8 + e
// ---------------------------------------------------------------------------
__global__ void proj_kernel(const float* __restrict__ qr,
                            const float* __restrict__ W,
                            float* __restrict__ qn,
                            unsigned short* __restrict__ qfrag) {
    __shared__ float qrow[DIM];
    __shared__ float red[256];
    const int b = blockIdx.x;
    const int t = threadIdx.x;

    qrow[t]       = qr[b * DIM + t];
    qrow[t + 256] = qr[b * DIM + t + 256];
    __syncthreads();

    float acc0 = 0.f, acc1 = 0.f;
#pragma unroll 8
    for (int k = 0; k < DIM; ++k) {
        const float q = qrow[k];
        acc0 = fmaf(q, W[k * DIM + t],       acc0);
        acc1 = fmaf(q, W[k * DIM + t + 256], acc1);
    }

    red[t] = acc0 * acc0 + acc1 * acc1;
    __syncthreads();
    for (int s = 128; s > 0; s >>= 1) {
        if (t < s) red[t] += red[t + s];
        __syncthreads();
    }
    const float inv = 1.0f / fmaxf(sqrtf(red[0]), 1e-6f);

    const int qg = b >> 4, q15 = b & 15;
#pragma unroll
    for (int half = 0; half < 2; ++half) {
        const int d = t + half * 256;
        const float x = (half == 0 ? acc0 : acc1) * inv;
        qn[b * DIM + d] = x;
        const int kc = d >> 5, kk = d & 31, g = kk >> 3, e = kk & 7;
        qfrag[(size_t)kc * 4096 + qg * 512 + (g * 16 + q15) * 8 + e] = bf16_rne(x);
    }
}

// ---------------------------------------------------------------------------
// Kernel B: tile-pipelined MFMA cosine scan.
//  - Q resident in LDS (128 KB). Corpus tile = 16 rows = 32 KB contiguous f32,
//    read coalesced to regs 2 tiles ahead; converted to bf16 fragment layout
//    in a 2 x 16 KB LDS double buffer (XOR bank swizzle).
//  - One raw s_barrier + lgkmcnt(0) per tile; no vmcnt drain ever.
//  - 8 waves: wave w owns query group qg=w; 1 MFMA + 2 ds_reads per kc.
// ---------------------------------------------------------------------------
__global__ __launch_bounds__(512, 2) void scan_kernel(
        const float* __restrict__ corpus,
        const unsigned short* __restrict__ qfrag,
        float* __restrict__ cand_s,
        int*   __restrict__ cand_i) {
    __shared__ __align__(16) unsigned char smem[163840];
    unsigned short* Qlds = (unsigned short*)smem;            // 128 KB
    unsigned short* Abuf = (unsigned short*)(smem + 131072); // 2 x 8192 ushort

    const int t = threadIdx.x;
    const int w = t >> 6, l = t & 63;
    const int h = l >> 4, q15 = l & 15;
    const int qg = w;

    // ---- stage Q into LDS once ----
    {
        const uint4* src = (const uint4*)qfrag;
        uint4* dst = (uint4*)Qlds;
#pragma unroll
        for (int i = 0; i < 16; ++i)
            dst[t + 512 * i] = src[t + 512 * i];
    }
    __syncthreads();

    // ---- stage-write constants: thread t writes 4 pieces of the tile ----
    // piece p: flat float4 index i4 = p*512+t -> row r = i4>>7, k0 = (i4&127)*4
    int goff[4], lby[4];
#pragma unroll
    for (int p = 0; p < 4; ++p) {
        const int i4 = p * 512 + t;
        const int r  = i4 >> 7;
        const int k0 = (i4 & 127) * 4;
        const int kc = k0 >> 5, g = (k0 >> 3) & 3, e0 = k0 & 7;
        const int pos = g * 16 + r;                 // fragment lane slot
        const int m   = (kc & 7) ^ (((pos >> 4) & 3) << 1);
        goff[p] = r * DIM + k0;
        lby[p]  = kc * 1024 + (pos ^ m) * 16 + e0 * 2;
    }
    // read swizzle for lane l: byte = kc*1024 + (l ^ mr(kc,l))*16
    const int lg2 = ((l >> 4) & 3) << 1;

    float ts[3] = {-1e30f, -1e30f, -1e30f};
    int   ti[3] = {0, 0, 0};

    float4 rA[4], rB[4];
    const int tt0 = blockIdx.x;
    {
        const float* src = corpus + (size_t)tt0 * (16 * DIM);
#pragma unroll
        for (int p = 0; p < 4; ++p) rA[p] = *(const float4*)(src + goff[p]);
    }
    {
        int tn = tt0 + G_SCAN; if (tn > NTILES - 1) tn = NTILES - 1;
        const float* src = corpus + (size_t)tn * (16 * DIM);
#pragma unroll
        for (int p = 0; p < 4; ++p) rB[p] = *(const float4*)(src + goff[p]);
    }

    auto BODY = [&](int tt, float4* rr, unsigned short* bb) {
        // write staged tile to LDS (compiler emits counted vmcnt for rr)
#pragma unroll
        for (int p = 0; p < 4; ++p) {
            uint2 d;
            d.x = pack2(rr[p].y, rr[p].x);
            d.y = pack2(rr[p].w, rr[p].z);
            *(uint2*)((unsigned char*)bb + lby[p]) = d;
        }
        // prefetch tile tt + 2*G_SCAN into the same regs
        {
            int tn = tt + 2 * G_SCAN; if (tn > NTILES - 1) tn = NTILES - 1;
            const float* src = corpus + (size_t)tn * (16 * DIM);
#pragma unroll
            for (int p = 0; p < 4; ++p) rr[p] = *(const float4*)(src + goff[p]);
        }
        __builtin_amdgcn_sched_barrier(0);
        asm volatile("s_waitcnt lgkmcnt(0)" ::: "memory");
        __builtin_amdgcn_s_barrier();
        __builtin_amdgcn_sched_barrier(0);

        // compute this tile: 16 kc x (A ds_read, Q ds_read, MFMA) + bf16 norms
        floatx4 acc = {0.f, 0.f, 0.f, 0.f};
        float nsq = 0.f;
#pragma unroll
        for (int kc = 0; kc < NCH; ++kc) {
            const int mr = (kc & 7) ^ lg2;
            const short8 a = *(const short8*)((unsigned char*)bb +
                                              kc * 1024 + ((l ^ mr) * 16));
            const short8 q = *(const short8*)(Qlds + kc * 4096 + qg * 512 + l * 8);
            const uint4 au = __builtin_bit_cast(uint4, a);
            {
                float x0 = __uint_as_float(au.x << 16);
                float x1 = __uint_as_float(au.x & 0xffff0000u);
                float x2 = __uint_as_float(au.y << 16);
                float x3 = __uint_as_float(au.y & 0xffff0000u);
                float x4 = __uint_as_float(au.z << 16);
                float x5 = __uint_as_float(au.z & 0xffff0000u);
                float x6 = __uint_as_float(au.w << 16);
                float x7 = __uint_as_float(au.w & 0xffff0000u);
                nsq = fmaf(x0, x0, nsq); nsq = fmaf(x1, x1, nsq);
                nsq = fmaf(x2, x2, nsq); nsq = fmaf(x3, x3, nsq);
                nsq = fmaf(x4, x4, nsq); nsq = fmaf(x5, x5, nsq);
                nsq = fmaf(x6, x6, nsq); nsq = fmaf(x7, x7, nsq);
            }
            acc = __builtin_amdgcn_mfma_f32_16x16x32_bf16(a, q, acc, 0, 0, 0);
        }

        // row norms: lanes l, l^16, l^32 cover the 4 k-slices of row l&15
        float n = nsq;
        n += __shfl_xor(n, 16); n += __shfl_xor(n, 32);
        const float invn = 1.0f / fmaxf(sqrtf(n), 1e-6f);

#pragma unroll
        for (int reg = 0; reg < 4; ++reg) {
            const int m = h * 4 + reg;             // C row within tile
            const float iv = __shfl(invn, m, 64);
            ins3(acc[reg] * iv, tt * 16 + m, ts[0], ts[1], ts[2],
                 ti[0], ti[1], ti[2]);
        }
    };

#pragma unroll 1
    for (int tt = tt0; tt < NTILES; tt += 2 * G_SCAN) {
        BODY(tt, rA, Abuf);
        if (tt + G_SCAN < NTILES)
            BODY(tt + G_SCAN, rB, Abuf + 8192);
    }

    // ---- block merge: 4 h-slots x top3 per query -> per-block top-3 ----
    __syncthreads();
    float* msc = (float*)smem;                 // [128][4][3] = 6 KB
    int*   mid = (int*)(smem + 8192);          // 6 KB
    {
        const int q = qg * 16 + q15;
#pragma unroll
        for (int j = 0; j < 3; ++j) {
            msc[(q * 4 + h) * 3 + j] = ts[j];
            mid[(q * 4 + h) * 3 + j] = ti[j];
        }
    }
    __syncthreads();
    if (t < B_Q) {
        float b0 = -1e30f, b1 = -1e30f, b2 = -1e30f;
        int   i0 = 0, i1 = 0, i2 = 0;
        for (int e = 0; e < 12; ++e)
            ins3(msc[t * 12 + e], mid[t * 12 + e], b0, b1, b2, i0, i1, i2);
        const size_t base = ((size_t)blockIdx.x * B_Q + t) * 3;
        cand_s[base + 0] = b0; cand_s[base + 1] = b1; cand_s[base + 2] = b2;
        cand_i[base + 0] = i0; cand_i[base + 1] = i1; cand_i[base + 2] = i2;
    }
}

// ---------------------------------------------------------------------------
// Kernel C: merge per-block candidates -> global approx top-8 per query.
// ---------------------------------------------------------------------------
__global__ void merge_topk_kernel(const float* __restrict__ cand_s,
                                  const int*   __restrict__ cand_i,
                                  int nblk,
                                  float* __restrict__ topT_s,
                                  int*   __restrict__ topT_i) {
    __shared__ float ls[256 * 8];
    __shared__ int   li[256 * 8];
    const int q = blockIdx.x;
    const int t = threadIdx.x;

    float bs[8]; int bi[8];
#pragma unroll
    for (int j = 0; j < 8; ++j) { bs[j] = -1e30f; bi[j] = -1; }

    for (int blk = t; blk < nblk; blk += 256) {
        const size_t base = ((size_t)blk * B_Q + q) * 3;
#pragma unroll
        for (int j = 0; j < 3; ++j)
            ins8(cand_s[base + j], cand_i[base + j], bs, bi);
    }
#pragma unroll
    for (int j = 0; j < 8; ++j) { ls[t * 8 + j] = bs[j]; li[t * 8 + j] = bi[j]; }
    __syncthreads();

    for (int s = 128; s > 0; s >>= 1) {
        if (t < s) {
#pragma unroll
            for (int j = 0; j < 8; ++j)
                ins8(ls[(t + s) * 8 + j], li[(t + s) * 8 + j], bs, bi);
#pragma unroll
            for (int j = 0; j < 8; ++j) { ls[t * 8 + j] = bs[j]; li[t * 8 + j] = bi[j]; }
        }
        __syncthreads();
    }
    if (t == 0) {
#pragma unroll
        for (int j = 0; j < 8; ++j) { topT_s[q * 8 + j] = bs[j]; topT_i[q * 8 + j] = bi[j]; }
    }
}

// ---------------------------------------------------------------------------
// Kernel D: exact f32 rescore of 8 candidates per query -> top-3 -> out.
// d_out: [0..383] scores f32, [384..767] indices stored as f32 values.
// ---------------------------------------------------------------------------
__global__ void rescore_kernel(const float* __restrict__ corpus,
                               const float* __restrict__ qn,
                               const int*   __restrict__ topT_i,
                               float* __restrict__ out) {
    __shared__ float qrow[DIM];
    __shared__ float sc[8];
    const int q = blockIdx.x;
    const int t = threadIdx.x;
    const int g = t >> 5;       // candidate 0..7
    const int lane = t & 31;

    qrow[t]       = qn[q * DIM + t];
    qrow[t + 256] = qn[q * DIM + t + 256];
    __syncthreads();

    const int r = topT_i[q * 8 + g];
    float d = 0.f, n = 0.f;
    if (r >= 0) {
        const float* row = corpus + (size_t)r * DIM;
        for (int j = lane; j < DIM; j += 32) {
            const float c = row[j];
            d = fmaf(qrow[j], c, d);
            n = fmaf(c, c, n);
        }
    }
#pragma unroll
    for (int m = 16; m > 0; m >>= 1) {
        d += __shfl_xor(d, m);
        n += __shfl_xor(n, m);
    }
    if (lane == 0)
        sc[g] = (r >= 0) ? d / fmaxf(sqrtf(n), 1e-6f) : -1e30f;
    __syncthreads();

    if (t == 0) {
        float b0 = -1e30f, b1 = -1e30f, b2 = -1e30f;
        int   i0 = 0, i1 = 0, i2 = 0;
#pragma unroll
        for (int e = 0; e < 8; ++e)
            ins3(sc[e], topT_i[q * 8 + e], b0, b1, b2, i0, i1, i2);
        out[q * 3 + 0] = b0;
        out[q * 3 + 1] = b1;
        out[q * 3 + 2] = b2;
        out[B_Q * 3 + q * 3 + 0] = (float)i0;
        out[B_Q * 3 + q * 3 + 1] = (float)i1;
        out[B_Q * 3 + q * 3 + 2] = (float)i2;
    }
}

// ---------------------------------------------------------------------------
extern "C" void kernel_launch(void* const* d_in, const int* in_sizes, int n_in,
                              void* d_out, int out_size, void* d_ws, size_t ws_size,
                              hipStream_t stream) {
    const float* qr     = (const float*)d_in[0];  // [128,512]
    const float* corpus = (const float*)d_in[1];  // [500000,512]
    const float* W      = (const float*)d_in[2];  // [512,512]

    float* out = (float*)d_out;
    char*  ws  = (char*)d_ws;

    float*          qn     = (float*)ws;                      // 256 KB
    unsigned short* qfrag  = (unsigned short*)(ws + 262144);  // 128 KB
    float*          topT_s = (float*)(ws + 393216);           // 4 KB
    int*            topT_i = (int*)(ws + 397312);             // 4 KB
    const size_t head = 401408;

    float* cand_s = (float*)(ws + head);                      // 256*128*3 f32
    int*   cand_i = (int*)(ws + head + (size_t)G_SCAN * B_Q * 3 * sizeof(float));

    proj_kernel<<<B_Q, 256, 0, stream>>>(qr, W, qn, qfrag);
    scan_kernel<<<G_SCAN, 512, 0, stream>>>(corpus, qfrag, cand_s, cand_i);
    merge_topk_kernel<<<B_Q, 256, 0, stream>>>(cand_s, cand_i, G_SCAN, topT_s, topT_i);
    rescore_kernel<<<B_Q, 256, 0, stream>>>(corpus, qn, topT_i, out);
}

// Round 10
// 618.982 us; speedup vs baseline: 1.0930x; 1.0015x over previous
//
#include <hip/hip_runtime.h>
#include <math.h>

#define B_Q   128
#define DIM   512
#define NCORP 500000
#define G_SCAN 256             // 1 block/CU (128 KB LDS)
#define WPB    12              // waves per block (768 thr)
#define GW     (G_SCAN * WPB)  // 3072 waves
#define UNITS  (NCORP / 16)    // 31250 16-row units (exact)

typedef short short8 __attribute__((ext_vector_type(8)));
typedef float floatx4 __attribute__((ext_vector_type(4)));

__device__ __forceinline__ unsigned short bf16_rne(float x) {
    unsigned u = __float_as_uint(x);
    return (unsigned short)((u + 0x7FFFu + ((u >> 16) & 1u)) >> 16);
}

// pack two f32 -> two bf16 (truncation) in one v_perm
__device__ __forceinline__ unsigned pack2(float hi, float lo) {
    return __builtin_amdgcn_perm(__float_as_uint(hi), __float_as_uint(lo),
                                 0x07060302u);
}

__device__ __forceinline__ void ins3(float s, int id,
                                     float& b0, float& b1, float& b2,
                                     int& i0, int& i1, int& i2) {
    if (s > b0)      { b2 = b1; i2 = i1; b1 = b0; i1 = i0; b0 = s; i0 = id; }
    else if (s > b1) { b2 = b1; i2 = i1; b1 = s;  i1 = id; }
    else if (s > b2) { b2 = s;  i2 = id; }
}

__device__ __forceinline__ void ins2(float s, int id,
                                     float& b0, float& b1, int& i0, int& i1) {
    if (s > b0)      { b1 = b0; i1 = i0; b0 = s; i0 = id; }
    else if (s > b1) { b1 = s;  i1 = id; }
}

__device__ __forceinline__ void ins8(float s, int id, float* bs, int* bi) {
#pragma unroll
    for (int j = 0; j < 8; ++j) {
        if (s > bs[j]) {
            float tf = bs[j]; int tx = bi[j];
            bs[j] = s; bi[j] = id; s = tf; id = tx;
        }
    }
}

// ---------------------------------------------------------------------------
// Kernel A: query = query_r @ W ; L2-normalize ; write
//  (a) exact qn f32 row-major (for rescore)
//  (b) bf16 MFMA B-fragment-linear: idx = kc*4096 + qg*512 + (g*16+q15)*8 + e
// ---------------------------------------------------------------------------
__global__ void proj_kernel(const float* __restrict__ qr,
                            const float* __restrict__ W,
                            float* __restrict__ qn,
                            unsigned short* __restrict__ qfrag) {
    __shared__ float qrow[DIM];
    __shared__ float red[256];
    const int b = blockIdx.x;
    const int t = threadIdx.x;

    qrow[t]       = qr[b * DIM + t];
    qrow[t + 256] = qr[b * DIM + t + 256];
    __syncthreads();

    float acc0 = 0.f, acc1 = 0.f;
#pragma unroll 8
    for (int k = 0; k < DIM; ++k) {
        const float q = qrow[k];
        acc0 = fmaf(q, W[k * DIM + t],       acc0);
        acc1 = fmaf(q, W[k * DIM + t + 256], acc1);
    }

    red[t] = acc0 * acc0 + acc1 * acc1;
    __syncthreads();
    for (int s = 128; s > 0; s >>= 1) {
        if (t < s) red[t] += red[t + s];
        __syncthreads();
    }
    const float inv = 1.0f / fmaxf(sqrtf(red[0]), 1e-6f);

    const int qg = b >> 4, q15 = b & 15;
#pragma unroll
    for (int half = 0; half < 2; ++half) {
        const int d = t + half * 256;
        const float x = (half == 0 ? acc0 : acc1) * inv;
        qn[b * DIM + d] = x;
        const int kc = d >> 5, kk = d & 31, g = kk >> 3, e = kk & 7;
        qfrag[(size_t)kc * 4096 + qg * 512 + (g * 16 + q15) * 8 + e] = bf16_rne(x);
    }
}

// ---------------------------------------------------------------------------
// Kernel B: barrier-free MFMA cosine scan, occupancy + prefetch-depth tuned.
//  - 12 waves/block, 1 block/CU. Q resident in LDS (128 KB, loaded once).
//  - Each wave owns 16-row units; corpus loaded DIRECTLY global->VGPR with a
//    strict depth-2 double buffer (unroll 1 over kc+=2 -> no load hoisting,
//    no spill). ~48 KB in flight per CU.
//  - Row norms via an extra mfma(a,a): diagonal = sum(x^2). No unpack VALU.
//  - No __syncthreads in the main loop.
// ---------------------------------------------------------------------------
__global__ __launch_bounds__(768, 3) void scan_kernel(
        const float* __restrict__ corpus,
        const unsigned short* __restrict__ qfrag,
        float* __restrict__ cand_s,
        int*   __restrict__ cand_i) {
    __shared__ __align__(16) unsigned char smem[131072];
    unsigned short* Qlds = (unsigned short*)smem;

    const int t = threadIdx.x;
    const int w = t / 64, l = t & 63;
    const int h = l >> 4, q15 = l & 15;

    // ---- stage Q into LDS once ----
    {
        const uint4* src = (const uint4*)qfrag;
        uint4* dst = (uint4*)Qlds;
        for (int i = t; i < 8192; i += 768) dst[i] = src[i];
    }
    __syncthreads();

    float ts[8][2]; int ti[8][2];
#pragma unroll
    for (int qg = 0; qg < 8; ++qg) {
        ts[qg][0] = -1e30f; ts[qg][1] = -1e30f;
        ti[qg][0] = 0;      ti[qg][1] = 0;
    }

    const int gw = blockIdx.x * WPB + w;      // global wave id 0..3071

    float4 A0, A1, B0, B1;                    // depth-2 stage buffers
    {
        const float* p0 = corpus + ((size_t)gw * 16 + q15) * DIM + h * 8;
        A0 = *(const float4*)(p0);       A1 = *(const float4*)(p0 + 4);
        B0 = *(const float4*)(p0 + 32);  B1 = *(const float4*)(p0 + 36);
    }

    for (int u = gw; u < UNITS; u += GW) {
        int un = u + GW; if (un >= UNITS) un = u;      // tail: reload current
        const float* pc = corpus + ((size_t)u  * 16 + q15) * DIM + h * 8;
        const float* pn = corpus + ((size_t)un * 16 + q15) * DIM + h * 8;

        floatx4 acc[8];
        floatx4 accN = {0.f, 0.f, 0.f, 0.f};
#pragma unroll
        for (int qg = 0; qg < 8; ++qg)
#pragma unroll
            for (int j = 0; j < 4; ++j) acc[qg][j] = 0.f;

#pragma unroll 1
        for (int kc = 0; kc < 16; kc += 2) {
            // ---- half A: chunk kc ----
            {
                uint4 ap;
                ap.x = pack2(A0.y, A0.x); ap.y = pack2(A0.w, A0.z);
                ap.z = pack2(A1.y, A1.x); ap.w = pack2(A1.w, A1.z);
                const short8 a = __builtin_bit_cast(short8, ap);
                const float* nA = (kc == 14) ? pn : (pc + (kc + 2) * 32);
                A0 = *(const float4*)nA; A1 = *(const float4*)(nA + 4);
                const unsigned short* qb = Qlds + kc * 4096 + l * 8;
                accN = __builtin_amdgcn_mfma_f32_16x16x32_bf16(a, a, accN, 0, 0, 0);
#pragma unroll
                for (int qg = 0; qg < 8; ++qg) {
                    const short8 q = *(const short8*)(qb + qg * 512);
                    acc[qg] = __builtin_amdgcn_mfma_f32_16x16x32_bf16(a, q, acc[qg], 0, 0, 0);
                }
            }
            // ---- half B: chunk kc+1 ----
            {
                uint4 bp;
                bp.x = pack2(B0.y, B0.x); bp.y = pack2(B0.w, B0.z);
                bp.z = pack2(B1.y, B1.x); bp.w = pack2(B1.w, B1.z);
                const short8 b = __builtin_bit_cast(short8, bp);
                const float* nB = (kc == 14) ? (pn + 32) : (pc + (kc + 3) * 32);
                B0 = *(const float4*)nB; B1 = *(const float4*)(nB + 4);
                const unsigned short* qb = Qlds + (kc + 1) * 4096 + l * 8;
                accN = __builtin_amdgcn_mfma_f32_16x16x32_bf16(b, b, accN, 0, 0, 0);
#pragma unroll
                for (int qg = 0; qg < 8; ++qg) {
                    const short8 q = *(const short8*)(qb + qg * 512);
                    acc[qg] = __builtin_amdgcn_mfma_f32_16x16x32_bf16(b, q, acc[qg], 0, 0, 0);
                }
            }
        }

        // epilogue: row m = h*4+reg; its norm (diag of accN) lives in lane
        // L = h*16 + m = h*20 + reg, register reg.
#pragma unroll
        for (int reg = 0; reg < 4; ++reg) {
            const int m = h * 4 + reg;
            const float nrm = __shfl(accN[reg], h * 20 + reg, 64);
            const float inv = 1.0f / fmaxf(sqrtf(nrm), 1e-6f);
            const int r = u * 16 + m;
#pragma unroll
            for (int qg = 0; qg < 8; ++qg)
                ins2(acc[qg][reg] * inv, r,
                     ts[qg][0], ts[qg][1], ti[qg][0], ti[qg][1]);
        }
    }

    // ---- block merge: 48 slots x top2 per query -> per-block top-3 ----
    __syncthreads();                           // everyone done with Qlds
    float* msc = (float*)smem;                 // [128][48][2] f32 = 48 KB
    int*   mid = (int*)(smem + 65536);         // 48 KB
#pragma unroll
    for (int qg = 0; qg < 8; ++qg) {
        const int q = qg * 16 + q15;
        const int slot = w * 4 + h;            // 0..47
#pragma unroll
        for (int j = 0; j < 2; ++j) {
            msc[(q * 48 + slot) * 2 + j] = ts[qg][j];
            mid[(q * 48 + slot) * 2 + j] = ti[qg][j];
        }
    }
    __syncthreads();
    if (t < B_Q) {
        float b0 = -1e30f, b1 = -1e30f, b2 = -1e30f;
        int   i0 = 0, i1 = 0, i2 = 0;
        for (int e = 0; e < 96; ++e)
            ins3(msc[t * 96 + e], mid[t * 96 + e], b0, b1, b2, i0, i1, i2);
        const size_t base = ((size_t)blockIdx.x * B_Q + t) * 3;
        cand_s[base + 0] = b0; cand_s[base + 1] = b1; cand_s[base + 2] = b2;
        cand_i[base + 0] = i0; cand_i[base + 1] = i1; cand_i[base + 2] = i2;
    }
}

// ---------------------------------------------------------------------------
// Kernel C: merge per-block candidates -> global approx top-8 per query.
// ---------------------------------------------------------------------------
__global__ void merge_topk_kernel(const float* __restrict__ cand_s,
                                  const int*   __restrict__ cand_i,
                                  int nblk,
                                  float* __restrict__ topT_s,
                                  int*   __restrict__ topT_i) {
    __shared__ float ls[256 * 8];
    __shared__ int   li[256 * 8];
    const int q = blockIdx.x;
    const int t = threadIdx.x;

    float bs[8]; int bi[8];
#pragma unroll
    for (int j = 0; j < 8; ++j) { bs[j] = -1e30f; bi[j] = -1; }

    for (int blk = t; blk < nblk; blk += 256) {
        const size_t base = ((size_t)blk * B_Q + q) * 3;
#pragma unroll
        for (int j = 0; j < 3; ++j)
            ins8(cand_s[base + j], cand_i[base + j], bs, bi);
    }
#pragma unroll
    for (int j = 0; j < 8; ++j) { ls[t * 8 + j] = bs[j]; li[t * 8 + j] = bi[j]; }
    __syncthreads();

    for (int s = 128; s > 0; s >>= 1) {
        if (t < s) {
#pragma unroll
            for (int j = 0; j < 8; ++j)
                ins8(ls[(t + s) * 8 + j], li[(t + s) * 8 + j], bs, bi);
#pragma unroll
            for (int j = 0; j < 8; ++j) { ls[t * 8 + j] = bs[j]; li[t * 8 + j] = bi[j]; }
        }
        __syncthreads();
    }
    if (t == 0) {
#pragma unroll
        for (int j = 0; j < 8; ++j) { topT_s[q * 8 + j] = bs[j]; topT_i[q * 8 + j] = bi[j]; }
    }
}

// ---------------------------------------------------------------------------
// Kernel D: exact f32 rescore of 8 candidates per query -> top-3 -> out.
// d_out: [0..383] scores f32, [384..767] indices stored as f32 values.
// ---------------------------------------------------------------------------
__global__ void rescore_kernel(const float* __restrict__ corpus,
                               const float* __restrict__ qn,
                               const int*   __restrict__ topT_i,
                               float* __restrict__ out) {
    __shared__ float qrow[DIM];
    __shared__ float sc[8];
    const int q = blockIdx.x;
    const int t = threadIdx.x;
    const int g = t >> 5;       // candidate 0..7
    const int lane = t & 31;

    qrow[t]       = qn[q * DIM + t];
    qrow[t + 256] = qn[q * DIM + t + 256];
    __syncthreads();

    const int r = topT_i[q * 8 + g];
    float d = 0.f, n = 0.f;
    if (r >= 0) {
        const float* row = corpus + (size_t)r * DIM;
        for (int j = lane; j < DIM; j += 32) {
            const float c = row[j];
            d = fmaf(qrow[j], c, d);
            n = fmaf(c, c, n);
        }
    }
#pragma unroll
    for (int m = 16; m > 0; m >>= 1) {
        d += __shfl_xor(d, m);
        n += __shfl_xor(n, m);
    }
    if (lane == 0)
        sc[g] = (r >= 0) ? d / fmaxf(sqrtf(n), 1e-6f) : -1e30f;
    __syncthreads();

    if (t == 0) {
        float b0 = -1e30f, b1 = -1e30f, b2 = -1e30f;
        int   i0 = 0, i1 = 0, i2 = 0;
#pragma unroll
        for (int e = 0; e < 8; ++e)
            ins3(sc[e], topT_i[q * 8 + e], b0, b1, b2, i0, i1, i2);
        out[q * 3 + 0] = b0;
        out[q * 3 + 1] = b1;
        out[q * 3 + 2] = b2;
        out[B_Q * 3 + q * 3 + 0] = (float)i0;
        out[B_Q * 3 + q * 3 + 1] = (float)i1;
        out[B_Q * 3 + q * 3 + 2] = (float)i2;
    }
}

// ---------------------------------------------------------------------------
extern "C" void kernel_launch(void* const* d_in, const int* in_sizes, int n_in,
                              void* d_out, int out_size, void* d_ws, size_t ws_size,
                              hipStream_t stream) {
    const float* qr     = (const float*)d_in[0];  // [128,512]
    const float* corpus = (const float*)d_in[1];  // [500000,512]
    const float* W      = (const float*)d_in[2];  // [512,512]

    float* out = (float*)d_out;
    char*  ws  = (char*)d_ws;

    float*          qn     = (float*)ws;                      // 256 KB
    unsigned short* qfrag  = (unsigned short*)(ws + 262144);  // 128 KB
    float*          topT_s = (float*)(ws + 393216);           // 4 KB
    int*            topT_i = (int*)(ws + 397312);             // 4 KB
    const size_t head = 401408;

    float* cand_s = (float*)(ws + head);                      // 256*128*3 f32
    int*   cand_i = (int*)(ws + head + (size_t)G_SCAN * B_Q * 3 * sizeof(float));

    proj_kernel<<<B_Q, 256, 0, stream>>>(qr, W, qn, qfrag);
    scan_kernel<<<G_SCAN, 768, 0, stream>>>(corpus, qfrag, cand_s, cand_i);
    merge_topk_kernel<<<B_Q, 256, 0, stream>>>(cand_s, cand_i, G_SCAN, topT_s, topT_i);
    rescore_kernel<<<B_Q, 256, 0, stream>>>(corpus, qn, topT_i, out);
}

// Round 11
// 547.266 us; speedup vs baseline: 1.2363x; 1.1310x over previous
//
#include <hip/hip_runtime.h>
#include <math.h>

#define B_Q   128
#define DIM   512
#define NCORP 500000
#define NTILES (NCORP / 16)    // 31250 16-row tiles (exact)
#define G_SCAN 256             // 1 block/CU, contiguous segment per block

typedef short short8 __attribute__((ext_vector_type(8)));
typedef float floatx4 __attribute__((ext_vector_type(4)));

__device__ __forceinline__ unsigned short bf16_rne(float x) {
    unsigned u = __float_as_uint(x);
    return (unsigned short)((u + 0x7FFFu + ((u >> 16) & 1u)) >> 16);
}

// pack two f32 -> two bf16 (truncation) in one v_perm (order verified r6-r10)
__device__ __forceinline__ unsigned pack2(float hi, float lo) {
    return __builtin_amdgcn_perm(__float_as_uint(hi), __float_as_uint(lo),
                                 0x07060302u);
}

__device__ __forceinline__ void ins3(float s, int id,
                                     float& b0, float& b1, float& b2,
                                     int& i0, int& i1, int& i2) {
    if (s > b0)      { b2 = b1; i2 = i1; b1 = b0; i1 = i0; b0 = s; i0 = id; }
    else if (s > b1) { b2 = b1; i2 = i1; b1 = s;  i1 = id; }
    else if (s > b2) { b2 = s;  i2 = id; }
}

__device__ __forceinline__ void ins8(float s, int id, float* bs, int* bi) {
#pragma unroll
    for (int j = 0; j < 8; ++j) {
        if (s > bs[j]) {
            float tf = bs[j]; int tx = bi[j];
            bs[j] = s; bi[j] = id; s = tf; id = tx;
        }
    }
}

// ---------------------------------------------------------------------------
// Kernel A: query = query_r @ W ; L2-normalize ; write
//  (a) exact qn f32 row-major (for rescore)
//  (b) bf16 MFMA B-fragment-linear: idx = kc*4096 + qg*512 + (g*16+q15)*8 + e
// ---------------------------------------------------------------------------
__global__ void proj_kernel(const float* __restrict__ qr,
                            const float* __restrict__ W,
                            float* __restrict__ qn,
                            unsigned short* __restrict__ qfrag) {
    __shared__ float qrow[DIM];
    __shared__ float red[256];
    const int b = blockIdx.x;
    const int t = threadIdx.x;

    qrow[t]       = qr[b * DIM + t];
    qrow[t + 256] = qr[b * DIM + t + 256];
    __syncthreads();

    float acc0 = 0.f, acc1 = 0.f;
#pragma unroll 8
    for (int k = 0; k < DIM; ++k) {
        const float q = qrow[k];
        acc0 = fmaf(q, W[k * DIM + t],       acc0);
        acc1 = fmaf(q, W[k * DIM + t + 256], acc1);
    }

    red[t] = acc0 * acc0 + acc1 * acc1;
    __syncthreads();
    for (int s = 128; s > 0; s >>= 1) {
        if (t < s) red[t] += red[t + s];
        __syncthreads();
    }
    const float inv = 1.0f / fmaxf(sqrtf(red[0]), 1e-6f);

    const int qg = b >> 4, q15 = b & 15;
#pragma unroll
    for (int half = 0; half < 2; ++half) {
        const int d = t + half * 256;
        const float x = (half == 0 ? acc0 : acc1) * inv;
        qn[b * DIM + d] = x;
        const int kc = d >> 5, kk = d & 31, g = kk >> 3, e = kk & 7;
        qfrag[(size_t)kc * 4096 + qg * 512 + (g * 16 + q15) * 8 + e] = bf16_rne(x);
    }
}

// ---------------------------------------------------------------------------
// Kernel B: contiguous-stream MFMA cosine scan.
//  Block b owns a contiguous corpus segment (122-123 tiles of 16 rows).
//  Per tile: cooperative coalesced 32 KB load (depth-2 reg dbuf) ->
//  bf16 XOR-swizzled LDS frag tile (2 x 16 KB) -> 1 raw barrier ->
//  per-wave mfma(a, Q[w]) + mfma(a,a) norm. Q resident in 128 KB LDS.
// ---------------------------------------------------------------------------
__global__ __launch_bounds__(512, 2) void scan_kernel(
        const float* __restrict__ corpus,
        const unsigned short* __restrict__ qfrag,
        float* __restrict__ cand_s,
        int*   __restrict__ cand_i) {
    __shared__ __align__(16) unsigned char smem[163840];
    unsigned short* Qlds = (unsigned short*)smem;           // 128 KB
    unsigned char*  Ab0  = smem + 131072;                   // 16 KB
    unsigned char*  Ab1  = smem + 147456;                   // 16 KB

    const int t = threadIdx.x;
    const int w = t >> 6, l = t & 63;
    const int h = l >> 4, q15 = l & 15;

    // ---- stage Q into LDS once ----
    {
        const uint4* src = (const uint4*)qfrag;
        uint4* dst = (uint4*)Qlds;
#pragma unroll
        for (int i = 0; i < 16; ++i) dst[t + 512 * i] = src[t + 512 * i];
    }
    __syncthreads();

    // ---- staging constants: thread t handles 4 float4 pieces of a tile ----
    int goff[4], lby[4];
#pragma unroll
    for (int p = 0; p < 4; ++p) {
        const int i4 = p * 512 + t;          // flat float4 idx in 32 KB tile
        const int r  = i4 >> 7;              // row 0..15
        const int c4 = i4 & 127;             // float4 within row
        const int kc = c4 >> 3, g = (c4 >> 1) & 3, e0 = (c4 & 1) * 4;
        goff[p] = i4 * 4;
        lby[p]  = kc * 1024 + (((g * 16 + r) ^ (kc & 7)) << 4) + e0 * 2;
    }

    // ---- contiguous segment for this block ----
    const int b = blockIdx.x;
    const int tstart = b * 122 + (b < 18 ? b : 18);          // 256*122+18=31250
    const int tcount = 122 + (b < 18 ? 1 : 0);
    const float* segbase = corpus + (size_t)tstart * (16 * DIM);

    float ts0 = -1e30f, ts1 = -1e30f, ts2 = -1e30f;
    int   ti0 = 0, ti1 = 0, ti2 = 0;

    float4 rA[4], rB[4];
#pragma unroll
    for (int p = 0; p < 4; ++p) rA[p] = *(const float4*)(segbase + goff[p]);
#pragma unroll
    for (int p = 0; p < 4; ++p) rB[p] = *(const float4*)(segbase + 8192 + goff[p]);

    auto BODY = [&](int tt, float4* rr, unsigned char* bb) {
        // write tile tt (held in rr) to LDS frag buffer (counted vmcnt wait)
#pragma unroll
        for (int p = 0; p < 4; ++p) {
            uint2 d;
            d.x = pack2(rr[p].y, rr[p].x);
            d.y = pack2(rr[p].w, rr[p].z);
            *(uint2*)(bb + lby[p]) = d;
        }
        // prefetch tile tt+2 (sequential addresses) into the same regs
        {
            int tn = tt + 2; if (tn >= tcount) tn = tt;
            const float* src = segbase + (size_t)tn * 8192;
#pragma unroll
            for (int p = 0; p < 4; ++p) rr[p] = *(const float4*)(src + goff[p]);
        }
        __builtin_amdgcn_sched_barrier(0);
        asm volatile("s_waitcnt lgkmcnt(0)" ::: "memory");
        __builtin_amdgcn_s_barrier();
        __builtin_amdgcn_sched_barrier(0);

        // compute: 16 kc x { A read (swizzled), Q read, norm MFMA, score MFMA }
        floatx4 acc  = {0.f, 0.f, 0.f, 0.f};
        floatx4 accN = {0.f, 0.f, 0.f, 0.f};
#pragma unroll
        for (int kc = 0; kc < 16; ++kc) {
            const short8 a = *(const short8*)(bb + kc * 1024 +
                                              ((l ^ (kc & 7)) << 4));
            const short8 q = *(const short8*)(Qlds + kc * 4096 + w * 512 + l * 8);
            accN = __builtin_amdgcn_mfma_f32_16x16x32_bf16(a, a, accN, 0, 0, 0);
            acc  = __builtin_amdgcn_mfma_f32_16x16x32_bf16(a, q, acc,  0, 0, 0);
        }

        // epilogue: row m = h*4+reg; norm (diag of accN) at lane h*20+reg
        const int grow = (tstart + tt) * 16;
#pragma unroll
        for (int reg = 0; reg < 4; ++reg) {
            const float nrm = __shfl(accN[reg], h * 20 + reg, 64);
            const float inv = 1.0f / fmaxf(sqrtf(nrm), 1e-6f);
            ins3(acc[reg] * inv, grow + h * 4 + reg,
                 ts0, ts1, ts2, ti0, ti1, ti2);
        }
    };

#pragma unroll 1
    for (int tt = 0; tt + 1 < tcount; tt += 2) {
        BODY(tt,     rA, Ab0);
        BODY(tt + 1, rB, Ab1);
    }
    if (tcount & 1) BODY(tcount - 1, rA, Ab0);

    // ---- block merge: per query 4 h-slots x top3 -> per-block top-3 ----
    __syncthreads();
    float* msc = (float*)smem;                 // [128][4][3] = 6 KB
    int*   mid = (int*)(smem + 8192);          // 6 KB
    {
        const int myq = w * 16 + q15;
        msc[(myq * 4 + h) * 3 + 0] = ts0;  mid[(myq * 4 + h) * 3 + 0] = ti0;
        msc[(myq * 4 + h) * 3 + 1] = ts1;  mid[(myq * 4 + h) * 3 + 1] = ti1;
        msc[(myq * 4 + h) * 3 + 2] = ts2;  mid[(myq * 4 + h) * 3 + 2] = ti2;
    }
    __syncthreads();
    if (t < B_Q) {
        float b0 = -1e30f, b1 = -1e30f, b2 = -1e30f;
        int   i0 = 0, i1 = 0, i2 = 0;
        for (int e = 0; e < 12; ++e)
            ins3(msc[t * 12 + e], mid[t * 12 + e], b0, b1, b2, i0, i1, i2);
        const size_t base = ((size_t)blockIdx.x * B_Q + t) * 3;
        cand_s[base + 0] = b0; cand_s[base + 1] = b1; cand_s[base + 2] = b2;
        cand_i[base + 0] = i0; cand_i[base + 1] = i1; cand_i[base + 2] = i2;
    }
}

// ---------------------------------------------------------------------------
// Kernel C: merge per-block candidates -> global approx top-8 per query.
// ---------------------------------------------------------------------------
__global__ void merge_topk_kernel(const float* __restrict__ cand_s,
                                  const int*   __restrict__ cand_i,
                                  int nblk,
                                  float* __restrict__ topT_s,
                                  int*   __restrict__ topT_i) {
    __shared__ float ls[256 * 8];
    __shared__ int   li[256 * 8];
    const int q = blockIdx.x;
    const int t = threadIdx.x;

    float bs[8]; int bi[8];
#pragma unroll
    for (int j = 0; j < 8; ++j) { bs[j] = -1e30f; bi[j] = -1; }

    for (int blk = t; blk < nblk; blk += 256) {
        const size_t base = ((size_t)blk * B_Q + q) * 3;
#pragma unroll
        for (int j = 0; j < 3; ++j)
            ins8(cand_s[base + j], cand_i[base + j], bs, bi);
    }
#pragma unroll
    for (int j = 0; j < 8; ++j) { ls[t * 8 + j] = bs[j]; li[t * 8 + j] = bi[j]; }
    __syncthreads();

    for (int s = 128; s > 0; s >>= 1) {
        if (t < s) {
#pragma unroll
            for (int j = 0; j < 8; ++j)
                ins8(ls[(t + s) * 8 + j], li[(t + s) * 8 + j], bs, bi);
#pragma unroll
            for (int j = 0; j < 8; ++j) { ls[t * 8 + j] = bs[j]; li[t * 8 + j] = bi[j]; }
        }
        __syncthreads();
    }
    if (t == 0) {
#pragma unroll
        for (int j = 0; j < 8; ++j) { topT_s[q * 8 + j] = bs[j]; topT_i[q * 8 + j] = bi[j]; }
    }
}

// ---------------------------------------------------------------------------
// Kernel D: exact f32 rescore of 8 candidates per query -> top-3 -> out.
// d_out: [0..383] scores f32, [384..767] indices stored as f32 values.
// ---------------------------------------------------------------------------
__global__ void rescore_kernel(const float* __restrict__ corpus,
                               const float* __restrict__ qn,
                               const int*   __restrict__ topT_i,
                               float* __restrict__ out) {
    __shared__ float qrow[DIM];
    __shared__ float sc[8];
    const int q = blockIdx.x;
    const int t = threadIdx.x;
    const int g = t >> 5;       // candidate 0..7
    const int lane = t & 31;

    qrow[t]       = qn[q * DIM + t];
    qrow[t + 256] = qn[q * DIM + t + 256];
    __syncthreads();

    const int r = topT_i[q * 8 + g];
    float d = 0.f, n = 0.f;
    if (r >= 0) {
        const float* row = corpus + (size_t)r * DIM;
        for (int j = lane; j < DIM; j += 32) {
            const float c = row[j];
            d = fmaf(qrow[j], c, d);
            n = fmaf(c, c, n);
        }
    }
#pragma unroll
    for (int m = 16; m > 0; m >>= 1) {
        d += __shfl_xor(d, m);
        n += __shfl_xor(n, m);
    }
    if (lane == 0)
        sc[g] = (r >= 0) ? d / fmaxf(sqrtf(n), 1e-6f) : -1e30f;
    __syncthreads();

    if (t == 0) {
        float b0 = -1e30f, b1 = -1e30f, b2 = -1e30f;
        int   i0 = 0, i1 = 0, i2 = 0;
#pragma unroll
        for (int e = 0; e < 8; ++e)
            ins3(sc[e], topT_i[q * 8 + e], b0, b1, b2, i0, i1, i2);
        out[q * 3 + 0] = b0;
        out[q * 3 + 1] = b1;
        out[q * 3 + 2] = b2;
        out[B_Q * 3 + q * 3 + 0] = (float)i0;
        out[B_Q * 3 + q * 3 + 1] = (float)i1;
        out[B_Q * 3 + q * 3 + 2] = (float)i2;
    }
}

// ---------------------------------------------------------------------------
extern "C" void kernel_launch(void* const* d_in, const int* in_sizes, int n_in,
                              void* d_out, int out_size, void* d_ws, size_t ws_size,
                              hipStream_t stream) {
    const float* qr     = (const float*)d_in[0];  // [128,512]
    const float* corpus = (const float*)d_in[1];  // [500000,512]
    const float* W      = (const float*)d_in[2];  // [512,512]

    float* out = (float*)d_out;
    char*  ws  = (char*)d_ws;

    float*          qn     = (float*)ws;                      // 256 KB
    unsigned short* qfrag  = (unsigned short*)(ws + 262144);  // 128 KB
    float*          topT_s = (float*)(ws + 393216);           // 4 KB
    int*            topT_i = (int*)(ws + 397312);             // 4 KB
    const size_t head = 401408;

    float* cand_s = (float*)(ws + head);                      // 256*128*3 f32
    int*   cand_i = (int*)(ws + head + (size_t)G_SCAN * B_Q * 3 * sizeof(float));

    proj_kernel<<<B_Q, 256, 0, stream>>>(qr, W, qn, qfrag);
    scan_kernel<<<G_SCAN, 512, 0, stream>>>(corpus, qfrag, cand_s, cand_i);
    merge_topk_kernel<<<B_Q, 256, 0, stream>>>(cand_s, cand_i, G_SCAN, topT_s, topT_i);
    rescore_kernel<<<B_Q, 256, 0, stream>>>(corpus, qn, topT_i, out);
}

// Round 12
// 372.655 us; speedup vs baseline: 1.8155x; 1.4686x over previous
//
#include <hip/hip_runtime.h>
#include <math.h>

#define B_Q   128
#define DIM   512
#define NCORP 500000
#define NTILES 31250           // 16-row tiles (exact)
#define G_SCAN 512             // 2 blocks/CU

typedef short short8 __attribute__((ext_vector_type(8)));
typedef float floatx4 __attribute__((ext_vector_type(4)));

__device__ __forceinline__ unsigned short bf16_rne(float x) {
    unsigned u = __float_as_uint(x);
    return (unsigned short)((u + 0x7FFFu + ((u >> 16) & 1u)) >> 16);
}

// pack two f32 -> two bf16 (truncation) in one v_perm (verified r6-r11)
__device__ __forceinline__ unsigned pack2(float hi, float lo) {
    return __builtin_amdgcn_perm(__float_as_uint(hi), __float_as_uint(lo),
                                 0x07060302u);
}

__device__ __forceinline__ void ins3(float s, int id,
                                     float& b0, float& b1, float& b2,
                                     int& i0, int& i1, int& i2) {
    if (s > b0)      { b2 = b1; i2 = i1; b1 = b0; i1 = i0; b0 = s; i0 = id; }
    else if (s > b1) { b2 = b1; i2 = i1; b1 = s;  i1 = id; }
    else if (s > b2) { b2 = s;  i2 = id; }
}

__device__ __forceinline__ void ins2(float s, int id,
                                     float& b0, float& b1, int& i0, int& i1) {
    if (s > b0)      { b1 = b0; i1 = i0; b0 = s; i0 = id; }
    else if (s > b1) { b1 = s;  i1 = id; }
}

__device__ __forceinline__ void ins8(float s, int id, float* bs, int* bi) {
#pragma unroll
    for (int j = 0; j < 8; ++j) {
        if (s > bs[j]) {
            float tf = bs[j]; int tx = bi[j];
            bs[j] = s; bi[j] = id; s = tf; id = tx;
        }
    }
}

// ---------------------------------------------------------------------------
// Kernel A: query = query_r @ W ; L2-normalize ; write
//  (a) exact qn f32 row-major (for rescore)
//  (b) bf16 MFMA B-fragment-linear: idx = kc*4096 + qg*512 + (g*16+q15)*8 + e
// ---------------------------------------------------------------------------
__global__ void proj_kernel(const float* __restrict__ qr,
                            const float* __restrict__ W,
                            float* __restrict__ qn,
                            unsigned short* __restrict__ qfrag) {
    __shared__ float qrow[DIM];
    __shared__ float red[256];
    const int b = blockIdx.x;
    const int t = threadIdx.x;

    qrow[t]       = qr[b * DIM + t];
    qrow[t + 256] = qr[b * DIM + t + 256];
    __syncthreads();

    float acc0 = 0.f, acc1 = 0.f;
#pragma unroll 8
    for (int k = 0; k < DIM; ++k) {
        const float q = qrow[k];
        acc0 = fmaf(q, W[k * DIM + t],       acc0);
        acc1 = fmaf(q, W[k * DIM + t + 256], acc1);
    }

    red[t] = acc0 * acc0 + acc1 * acc1;
    __syncthreads();
    for (int s = 128; s > 0; s >>= 1) {
        if (t < s) red[t] += red[t + s];
        __syncthreads();
    }
    const float inv = 1.0f / fmaxf(sqrtf(red[0]), 1e-6f);

    const int qg = b >> 4, q15 = b & 15;
#pragma unroll
    for (int half = 0; half < 2; ++half) {
        const int d = t + half * 256;
        const float x = (half == 0 ? acc0 : acc1) * inv;
        qn[b * DIM + d] = x;
        const int kc = d >> 5, kk = d & 31, g = kk >> 3, e = kk & 7;
        qfrag[(size_t)kc * 4096 + qg * 512 + (g * 16 + q15) * 8 + e] = bf16_rne(x);
    }
}

// ---------------------------------------------------------------------------
// Kernel B: MFMA cosine scan, 2 blocks/CU.
//  - Wave w holds its query group's fragments in REGISTERS (64 VGPR).
//  - LDS/block = 32 KB: double-buffered 16-row bf16 A-tile (R11 swizzle).
//  - Contiguous ~61-tile segment per block; coalesced cooperative staging.
//  - 1 lgkmcnt+s_barrier per tile; vmcnt never drained (prefetch in flight).
//  - Row norms via mfma(a,a) diagonal (verified r10/r11).
// ---------------------------------------------------------------------------
__global__ __launch_bounds__(512, 4) void scan_kernel(
        const float* __restrict__ corpus,
        const unsigned short* __restrict__ qfrag,
        float* __restrict__ cand_s,
        int*   __restrict__ cand_i) {
    __shared__ __align__(16) unsigned char smem[32768];   // 2 x 16 KB A-tiles

    const int t = threadIdx.x;
    const int w = t >> 6, l = t & 63;
    const int h = l >> 4, q15 = l & 15;

    // ---- Q fragments for this wave's query group -> registers ----
    short8 qreg[16];
#pragma unroll
    for (int kc = 0; kc < 16; ++kc)
        qreg[kc] = *(const short8*)(qfrag + (size_t)kc * 4096 + w * 512 + l * 8);

    // ---- staging constants (R11-verified): 4 float4 pieces per thread ----
    int goff[4], lby[4];
#pragma unroll
    for (int p = 0; p < 4; ++p) {
        const int i4 = p * 512 + t;          // flat float4 idx in 32 KB tile
        const int r  = i4 >> 7;              // row 0..15
        const int c4 = i4 & 127;             // float4 within row
        const int kc = c4 >> 3, g = (c4 >> 1) & 3, e0 = (c4 & 1) * 4;
        goff[p] = i4 * 4;
        lby[p]  = kc * 1024 + (((g * 16 + r) ^ (kc & 7)) << 4) + e0 * 2;
    }

    // ---- contiguous segment: 512 blocks x 61-62 tiles = 31250 ----
    const int b = blockIdx.x;
    const int tstart = b * 61 + (b < 18 ? b : 18);
    const int tcount = 61 + (b < 18 ? 1 : 0);
    const float* seg = corpus + (size_t)tstart * 8192;   // 16*512 floats/tile

    float ts0 = -1e30f, ts1 = -1e30f;
    int   ti0 = 0, ti1 = 0;

    float4 rr[4];
#pragma unroll
    for (int p = 0; p < 4; ++p) rr[p] = *(const float4*)(seg + goff[p]);

#pragma unroll 1
    for (int T = 0; T < tcount; ++T) {
        unsigned char* bb = smem + (T & 1) * 16384;

        // write tile T (in rr) to LDS frag buffer (counted vmcnt by compiler)
#pragma unroll
        for (int p = 0; p < 4; ++p) {
            uint2 d;
            d.x = pack2(rr[p].y, rr[p].x);
            d.y = pack2(rr[p].w, rr[p].z);
            *(uint2*)(bb + lby[p]) = d;
        }
        // prefetch tile T+1 (sequential) into the same regs (WAR-safe)
        {
            const int Tn = (T + 1 < tcount) ? T + 1 : T;
            const float* src = seg + (size_t)Tn * 8192;
#pragma unroll
            for (int p = 0; p < 4; ++p) rr[p] = *(const float4*)(src + goff[p]);
        }
        __builtin_amdgcn_sched_barrier(0);
        asm volatile("s_waitcnt lgkmcnt(0)" ::: "memory");
        __builtin_amdgcn_s_barrier();
        __builtin_amdgcn_sched_barrier(0);

        // compute: 16 kc x { swizzled A read, norm MFMA, score MFMA }
        floatx4 acc  = {0.f, 0.f, 0.f, 0.f};
        floatx4 accN = {0.f, 0.f, 0.f, 0.f};
#pragma unroll
        for (int kc = 0; kc < 16; ++kc) {
            const short8 a = *(const short8*)(bb + kc * 1024 +
                                              ((l ^ (kc & 7)) << 4));
            accN = __builtin_amdgcn_mfma_f32_16x16x32_bf16(a, a, accN, 0, 0, 0);
            acc  = __builtin_amdgcn_mfma_f32_16x16x32_bf16(a, qreg[kc], acc, 0, 0, 0);
        }

        // epilogue: row m = h*4+reg; norm diag at lane h*20+reg (r10/r11)
        const int grow = (tstart + T) * 16;
#pragma unroll
        for (int reg = 0; reg < 4; ++reg) {
            const float nrm = __shfl(accN[reg], h * 20 + reg, 64);
            const float inv = 1.0f / fmaxf(sqrtf(nrm), 1e-6f);
            ins2(acc[reg] * inv, grow + h * 4 + reg, ts0, ts1, ti0, ti1);
        }
    }

    // ---- block merge: per query 4 h-slots x top2 -> per-block top-3 ----
    __syncthreads();
    float* msc = (float*)smem;                 // [128][4][2] = 4 KB
    int*   mid = (int*)(smem + 4096);          // 4 KB
    {
        const int myq = w * 16 + q15;
        msc[(myq * 4 + h) * 2 + 0] = ts0;  mid[(myq * 4 + h) * 2 + 0] = ti0;
        msc[(myq * 4 + h) * 2 + 1] = ts1;  mid[(myq * 4 + h) * 2 + 1] = ti1;
    }
    __syncthreads();
    if (t < B_Q) {
        float b0 = -1e30f, b1 = -1e30f, b2 = -1e30f;
        int   i0 = 0, i1 = 0, i2 = 0;
        for (int e = 0; e < 8; ++e)
            ins3(msc[t * 8 + e], mid[t * 8 + e], b0, b1, b2, i0, i1, i2);
        const size_t base = ((size_t)blockIdx.x * B_Q + t) * 3;
        cand_s[base + 0] = b0; cand_s[base + 1] = b1; cand_s[base + 2] = b2;
        cand_i[base + 0] = i0; cand_i[base + 1] = i1; cand_i[base + 2] = i2;
    }
}

// ---------------------------------------------------------------------------
// Kernel C: merge per-block candidates -> global approx top-8 per query.
// ---------------------------------------------------------------------------
__global__ void merge_topk_kernel(const float* __restrict__ cand_s,
                                  const int*   __restrict__ cand_i,
                                  int nblk,
                                  float* __restrict__ topT_s,
                                  int*   __restrict__ topT_i) {
    __shared__ float ls[256 * 8];
    __shared__ int   li[256 * 8];
    const int q = blockIdx.x;
    const int t = threadIdx.x;

    float bs[8]; int bi[8];
#pragma unroll
    for (int j = 0; j < 8; ++j) { bs[j] = -1e30f; bi[j] = -1; }

    for (int blk = t; blk < nblk; blk += 256) {
        const size_t base = ((size_t)blk * B_Q + q) * 3;
#pragma unroll
        for (int j = 0; j < 3; ++j)
            ins8(cand_s[base + j], cand_i[base + j], bs, bi);
    }
#pragma unroll
    for (int j = 0; j < 8; ++j) { ls[t * 8 + j] = bs[j]; li[t * 8 + j] = bi[j]; }
    __syncthreads();

    for (int s = 128; s > 0; s >>= 1) {
        if (t < s) {
#pragma unroll
            for (int j = 0; j < 8; ++j)
                ins8(ls[(t + s) * 8 + j], li[(t + s) * 8 + j], bs, bi);
#pragma unroll
            for (int j = 0; j < 8; ++j) { ls[t * 8 + j] = bs[j]; li[t * 8 + j] = bi[j]; }
        }
        __syncthreads();
    }
    if (t == 0) {
#pragma unroll
        for (int j = 0; j < 8; ++j) { topT_s[q * 8 + j] = bs[j]; topT_i[q * 8 + j] = bi[j]; }
    }
}

// ---------------------------------------------------------------------------
// Kernel D: exact f32 rescore of 8 candidates per query -> top-3 -> out.
// d_out: [0..383] scores f32, [384..767] indices stored as f32 values.
// ---------------------------------------------------------------------------
__global__ void rescore_kernel(const float* __restrict__ corpus,
                               const float* __restrict__ qn,
                               const int*   __restrict__ topT_i,
                               float* __restrict__ out) {
    __shared__ float qrow[DIM];
    __shared__ float sc[8];
    const int q = blockIdx.x;
    const int t = threadIdx.x;
    const int g = t >> 5;       // candidate 0..7
    const int lane = t & 31;

    qrow[t]       = qn[q * DIM + t];
    qrow[t + 256] = qn[q * DIM + t + 256];
    __syncthreads();

    const int r = topT_i[q * 8 + g];
    float d = 0.f, n = 0.f;
    if (r >= 0) {
        const float* row = corpus + (size_t)r * DIM;
        for (int j = lane; j < DIM; j += 32) {
            const float c = row[j];
            d = fmaf(qrow[j], c, d);
            n = fmaf(c, c, n);
        }
    }
#pragma unroll
    for (int m = 16; m > 0; m >>= 1) {
        d += __shfl_xor(d, m);
        n += __shfl_xor(n, m);
    }
    if (lane == 0)
        sc[g] = (r >= 0) ? d / fmaxf(sqrtf(n), 1e-6f) : -1e30f;
    __syncthreads();

    if (t == 0) {
        float b0 = -1e30f, b1 = -1e30f, b2 = -1e30f;
        int   i0 = 0, i1 = 0, i2 = 0;
#pragma unroll
        for (int e = 0; e < 8; ++e)
            ins3(sc[e], topT_i[q * 8 + e], b0, b1, b2, i0, i1, i2);
        out[q * 3 + 0] = b0;
        out[q * 3 + 1] = b1;
        out[q * 3 + 2] = b2;
        out[B_Q * 3 + q * 3 + 0] = (float)i0;
        out[B_Q * 3 + q * 3 + 1] = (float)i1;
        out[B_Q * 3 + q * 3 + 2] = (float)i2;
    }
}

// ---------------------------------------------------------------------------
extern "C" void kernel_launch(void* const* d_in, const int* in_sizes, int n_in,
                              void* d_out, int out_size, void* d_ws, size_t ws_size,
                              hipStream_t stream) {
    const float* qr     = (const float*)d_in[0];  // [128,512]
    const float* corpus = (const float*)d_in[1];  // [500000,512]
    const float* W      = (const float*)d_in[2];  // [512,512]

    float* out = (float*)d_out;
    char*  ws  = (char*)d_ws;

    float*          qn     = (float*)ws;                      // 256 KB
    unsigned short* qfrag  = (unsigned short*)(ws + 262144);  // 128 KB
    float*          topT_s = (float*)(ws + 393216);           // 4 KB
    int*            topT_i = (int*)(ws + 397312);             // 4 KB
    const size_t head = 401408;

    float* cand_s = (float*)(ws + head);                      // 512*128*3 f32
    int*   cand_i = (int*)(ws + head + (size_t)G_SCAN * B_Q * 3 * sizeof(float));

    proj_kernel<<<B_Q, 256, 0, stream>>>(qr, W, qn, qfrag);
    scan_kernel<<<G_SCAN, 512, 0, stream>>>(corpus, qfrag, cand_s, cand_i);
    merge_topk_kernel<<<B_Q, 256, 0, stream>>>(cand_s, cand_i, G_SCAN, topT_s, topT_i);
    rescore_kernel<<<B_Q, 256, 0, stream>>>(corpus, qn, topT_i, out);
}